// Round 1
// baseline (177.160 us; speedup 1.0000x reference)
//
#include <hip/hip_runtime.h>

#define D_FEAT 32

__global__ void zero_out_kernel(float* __restrict__ out, int n) {
    int i = blockIdx.x * blockDim.x + threadIdx.x;
    if (i < n) out[i] = 0.0f;
}

// One thread per (edge, feature): e = gid/32, f = gid%32.
// Lanes 0..31 of a wave share edge e, lanes 32..63 share edge e+1, so the
// idx loads broadcast within the cache line and the X gather / out scatter
// are 128B-contiguous per edge.
__global__ void scatter_add_kernel(const float* __restrict__ X,
                                   const int* __restrict__ edge_index,
                                   float* __restrict__ out,
                                   int n_edges) {
    int gid = blockIdx.x * blockDim.x + threadIdx.x;
    int e = gid >> 5;
    int f = gid & 31;
    if (e >= n_edges) return;
    int dst = edge_index[2 * e];       // index_i (segment id)
    int src = edge_index[2 * e + 1];   // index_j (gathered row)
    float v = X[(long long)src * D_FEAT + f];
    atomicAdd(&out[(long long)dst * D_FEAT + f], v);
}

extern "C" void kernel_launch(void* const* d_in, const int* in_sizes, int n_in,
                              void* d_out, int out_size, void* d_ws, size_t ws_size,
                              hipStream_t stream) {
    const float* X = (const float*)d_in[0];
    const int* edge_index = (const int*)d_in[1];
    float* out = (float*)d_out;

    int n_edges = in_sizes[1] / 2;

    // Zero-init output every call (harness poisons d_out with 0xAA).
    {
        int threads = 256;
        int blocks = (out_size + threads - 1) / threads;
        zero_out_kernel<<<blocks, threads, 0, stream>>>(out, out_size);
    }

    // Scatter-add: 32 threads per edge.
    {
        long long total = (long long)n_edges * D_FEAT;
        int threads = 256;
        long long blocks = (total + threads - 1) / threads;
        scatter_add_kernel<<<(int)blocks, threads, 0, stream>>>(X, edge_index, out, n_edges);
    }
}